// Round 8
// baseline (18.204 us; speedup 1.0000x reference)
//
#include <hip/hip_runtime.h>
#include <math.h>

#define B_ 64
#define N_ 32
#define H_ 200
#define W_ 200
#define NSEG (N_ - 1)

// ---- two-kernel path: 16x16 tiles ----
#define TS2 16
#define NT2 13                  // 13x13 tiles cover 200x200 (last partial)
#define NTILE (NT2 * NT2)       // 169
#define TILE_RAD2 0.054f        // sqrt(7.5^2+7.5^2)/200 = 0.05303 + margin

// ws layout (bytes)
#define WS_MASK_BYTES (B_ * NTILE * 4)              // 43264
#define WS_SEGA_OFF   WS_MASK_BYTES
#define WS_SEGA_BYTES (B_ * NSEG * 16)              // 31744
#define WS_SEGB_OFF   (WS_SEGA_OFF + WS_SEGA_BYTES) // 75008
#define WS_NEEDED     (WS_SEGB_OFF + WS_SEGA_BYTES) // 106752

// ================= kernel 1: per-(b,tile) cull masks + seg records ==========
__global__ __launch_bounds__(64) void cull_kernel(
    const float* __restrict__ param,
    const float* __restrict__ x_start,  const float* __restrict__ y_start,
    const float* __restrict__ theta,    const float* __restrict__ weights,
    const float* __restrict__ biases,   const float* __restrict__ thick_mult,
    const float* __restrict__ thick_bias,
    const float* __restrict__ x_m_p,    const float* __restrict__ y_m_p,
    const float* __restrict__ x_b_p,    const float* __restrict__ y_b_p,
    unsigned* __restrict__ ws_mask,     // (B, 169)
    float4*  __restrict__ ws_segA,      // (B, 31): (vy, vx, wvy, wvx)
    float4*  __restrict__ ws_segB)      // (B, 31): (inv_d2, c0, c1, ddot_x)
{
    const int b    = blockIdx.y;
    const int ty   = blockIdx.x;        // 0..12
    const int lane = threadIdx.x;       // 0..63

    float sy = 0.0f, sx = 0.0f, tk = 0.0f;
    const float tm = thick_mult[0], tb = thick_bias[0];
    if (lane < N_) {
        const float thv = theta[0];
        const float c   = __cosf(thv), s = __sinf(thv);
        const float xs  = x_start[0], ys = y_start[0];
        const float W00 = weights[0], W01 = weights[1];
        const float W10 = weights[2], W11 = weights[3];
        const float bb0 = biases[0],  bb1 = biases[1];
        const float xm  = x_m_p[0], ym = y_m_p[0];
        const float xb  = x_b_p[0], yb = y_b_p[0];
        float p0 = param[(b * N_ + lane) * 3 + 0];
        float p1 = param[(b * N_ + lane) * 3 + 1];
        float p2 = param[(b * N_ + lane) * 3 + 2];
        float x0 = p0, y0 = -p1;
        float x_rot =  x0 * c + y0 * s;
        float y_rot = -x0 * s + y0 * c;
        float yy = y_rot * ym + yb + ys;
        float xx = x_rot * xm + xb + xs;
        sy = yy * W00 + xx * W01 + bb0;
        sx = yy * W10 + xx * W11 + bb1;
        tk = (p2 * 2.0f + 0.5f) * (1.0f / 64.0f);
    }
    float sy1 = __shfl_down(sy, 1);
    float sx1 = __shfl_down(sx, 1);
    float tk1 = __shfl_down(tk, 1);

    const bool isseg = (lane < NSEG);
    float wvy = 0, wvx = 0, inv_d2 = 0, c0 = 0, c1 = 0, thmax = 0;
    if (isseg) {
        wvy = sy1 - sy; wvx = sx1 - sx;
        float d2 = wvy * wvy + wvx * wvx;
        inv_d2 = 1.0f / (d2 + 1e-5f);
        c0 = tk * tm + tb;
        c1 = (tk1 - tk) * tm;
        thmax = fmaxf(fmaxf(c0, c0 + c1), 1e-8f);
        if (ty == 0) {
            ws_segA[b * NSEG + lane] = make_float4(sy, sx, wvy, wvx);
            ws_segB[b * NSEG + lane] =
                make_float4(inv_d2, c0, c1, wvx * inv_d2 * (1.0f / W_));
        }
    }

    // per-seg loop-invariants for the tile tests
    const float segYmin = fminf(sy, sy1), segYmax = fmaxf(sy, sy1);
    const float segXmin = fminf(sx, sx1), segXmax = fmaxf(sx, sx1);
    const float reach   = thmax + TILE_RAD2;
    const float reach2  = reach * reach;
    const float th2     = thmax * thmax + 1e-7f;
    const float cy   = ((float)(ty * TS2) + 7.5f) * (1.0f / H_);
    const float tyLo = (float)(ty * TS2) * (1.0f / H_);
    const float tyHi = (float)(ty * TS2 + (TS2 - 1)) * (1.0f / H_);
    float gy = fmaxf(fmaxf(tyLo - segYmax, segYmin - tyHi), 0.0f);

    for (int tx = 0; tx < NT2; ++tx) {
        bool keep = false;
        if (isseg) {
            const float cx   = ((float)(tx * TS2) + 7.5f) * (1.0f / W_);
            const float txLo = (float)(tx * TS2) * (1.0f / W_);
            const float txHi = (float)(tx * TS2 + (TS2 - 1)) * (1.0f / W_);
            // circle test
            float dyc = cy - sy, dxc = cx - sx;
            float dot = (dyc * wvy + dxc * wvx) * inv_d2;
            float fr  = __builtin_amdgcn_fmed3f(dot, 0.0f, 1.0f);
            float ey  = dyc - fr * wvy;
            float ex  = dxc - fr * wvx;
            float e2c = ey * ey + ex * ex;
            // AABB interval-gap test
            float gx = fmaxf(fmaxf(txLo - segXmax, segXmin - txHi), 0.0f);
            keep = (e2c < reach2) && ((gx * gx + gy * gy) < th2);
        }
        unsigned mm = (unsigned)__ballot(keep);
        if (lane == 0) ws_mask[(b * NT2 + ty) * NT2 + tx] = mm;
    }
}

// ================= kernel 2: paint (wave = one 16x16 tile) ==================
__global__ __launch_bounds__(256) void paint_kernel(
    const float* __restrict__ dark_exp_p, const float* __restrict__ dark_nlw_p,
    const unsigned* __restrict__ ws_mask,
    const float4*  __restrict__ ws_segA,
    const float4*  __restrict__ ws_segB,
    float* __restrict__ out)
{
    __shared__ float4 sA_l[NSEG], sB_l[NSEG];

    const int b   = blockIdx.y;
    const int tid = threadIdx.x;

    if (tid < 2 * NSEG) {
        int s = tid >> 1;
        if (tid & 1) sB_l[s] = ws_segB[b * NSEG + s];
        else         sA_l[s] = ws_segA[b * NSEG + s];
    }
    __syncthreads();

    const int t = blockIdx.x * 4 + (tid >> 6);
    if (t >= NTILE) return;
    const int lane = tid & 63;
    const int ty = t / NT2, tx = t - ty * NT2;
    const int r  = ty * TS2 + (lane >> 2);
    const int c0 = tx * TS2 + ((lane & 3) << 2);
    const float py  = (float)r  * (1.0f / H_);
    const float px0 = (float)c0 * (1.0f / W_);

    const unsigned mask = ws_mask[b * NTILE + t];
    const float dexp = dark_exp_p[0], dnlw = dark_nlw_p[0];
    const bool hoist = (dexp > 0.0f) && (dnlw >= 0.0f) && (dnlw <= 1.0f);

    float o0, o1, o2, o3;
    if (hoist) {
        // maximize dark = 1 - sqrt(e2)/th  <=>  minimize q = e2*rcp(th)^2;
        // sqrt once per pixel; final clamp01 subsumes per-seg clamp + culled 0s.
        float q0 = INFINITY, q1 = INFINITY, q2 = INFINITY, q3 = INFINITY;
        unsigned m = mask;
        if (m) {
            int s = __ffs(m) - 1;
            float4 A = sA_l[s], Bc = sB_l[s];
            for (;;) {
                unsigned m2 = m & (m - 1u);
                int sn = m2 ? (__ffs(m2) - 1) : 0;      // prefetch next
                float4 An = sA_l[sn], Bn = sB_l[sn];
                float dy  = py  - A.x;
                float dx0 = px0 - A.y;
                float dx1 = dx0 + 1.0f / W_;
                float dx2 = dx0 + 2.0f / W_;
                float dx3 = dx0 + 3.0f / W_;
                float dot0 = fmaf(dy, A.z, dx0 * A.w) * Bc.x;
                float dot1 = dot0 + Bc.w;
                float dot2 = dot1 + Bc.w;
                float dot3 = dot2 + Bc.w;
                #define PX(dotv, dxv, qm) { \
                    float fr = __builtin_amdgcn_fmed3f(dotv, 0.0f, 1.0f); \
                    float ey = fmaf(-fr, A.z, dy); \
                    float ex = fmaf(-fr, A.w, dxv); \
                    float e2 = fmaf(ey, ey, ex * ex); \
                    float th = fmaxf(fmaf(fr, Bc.z, Bc.y), 1e-8f); \
                    float it = __builtin_amdgcn_rcpf(th); \
                    qm = fminf(qm, (e2 * it) * it); }
                PX(dot0, dx0, q0)
                PX(dot1, dx1, q1)
                PX(dot2, dx2, q2)
                PX(dot3, dx3, q3)
                #undef PX
                if (!m2) break;
                m = m2; A = An; Bc = Bn;
            }
        }
        const bool lin = (dexp == 1.0f);
        #define EPI(qm, rr) { \
            float md = fminf(fmaxf(1.0f - __builtin_amdgcn_sqrtf(qm), 0.0f), 1.0f); \
            float d  = lin ? (md + 1e-4f) : __expf(dexp * __logf(md + 1e-4f)); \
            float nl = __builtin_amdgcn_rcpf(1.0f + __expf(8.0f - d * 16.0f)); \
            rr = dnlw * nl + (1.0f - dnlw) * d; }
        EPI(q0, o0) EPI(q1, o1) EPI(q2, o2) EPI(q3, o3)
        #undef EPI
    } else {
        float b0 = -INFINITY, b1 = -INFINITY, b2 = -INFINITY, b3 = -INFINITY;
        if (__popc(mask) < NSEG) {
            float d0  = __expf(dexp * __logf(1e-4f));
            float nl0 = __builtin_amdgcn_rcpf(1.0f + __expf(8.0f - d0 * 16.0f));
            float t0  = dnlw * nl0 + (1.0f - dnlw) * d0;
            b0 = b1 = b2 = b3 = t0;
        }
        unsigned m = mask;
        while (m) {
            int s = __ffs(m) - 1;
            m &= m - 1u;
            float4 A = sA_l[s], Bc = sB_l[s];
            float dy  = py  - A.x;
            float dx0 = px0 - A.y;
            float dx1 = dx0 + 1.0f / W_;
            float dx2 = dx0 + 2.0f / W_;
            float dx3 = dx0 + 3.0f / W_;
            float dot0 = fmaf(dy, A.z, dx0 * A.w) * Bc.x;
            float dot1 = dot0 + Bc.w;
            float dot2 = dot1 + Bc.w;
            float dot3 = dot2 + Bc.w;
            #define PXF(dotv, dxv, bb) { \
                float fr = __builtin_amdgcn_fmed3f(dotv, 0.0f, 1.0f); \
                float ey = fmaf(-fr, A.z, dy); \
                float ex = fmaf(-fr, A.w, dxv); \
                float dist = __builtin_amdgcn_sqrtf(fmaf(ey, ey, ex * ex)); \
                float th = fmaxf(fmaf(fr, Bc.z, Bc.y), 1e-8f); \
                float dark = fminf(fmaxf(fmaf(-dist, __builtin_amdgcn_rcpf(th), 1.0f), 0.0f), 1.0f); \
                float d  = __expf(dexp * __logf(dark + 1e-4f)); \
                float nl = __builtin_amdgcn_rcpf(1.0f + __expf(8.0f - d * 16.0f)); \
                bb = fmaxf(bb, dnlw * nl + (1.0f - dnlw) * d); }
            PXF(dot0, dx0, b0)
            PXF(dot1, dx1, b1)
            PXF(dot2, dx2, b2)
            PXF(dot3, dx3, b3)
            #undef PXF
        }
        o0 = b0; o1 = b1; o2 = b2; o3 = b3;
    }

    if (r < H_ && c0 < W_) {   // c0 % 4 == 0 and c0 < 200 -> c0 <= 196, no straddle
        *reinterpret_cast<float4*>(&out[(b * H_ + r) * W_ + c0]) =
            make_float4(o0, o1, o2, o3);
    }
}

// ================= fallback: R6 monolithic (if ws too small) ================
#define TSX 32
#define TSY 16
#define NTX 7
#define NTY 13
#define TILE_RAD 0.087f

__global__ __launch_bounds__(128) void stroke_mono(
    const float* __restrict__ param,
    const float* __restrict__ x_start,  const float* __restrict__ y_start,
    const float* __restrict__ theta,    const float* __restrict__ weights,
    const float* __restrict__ biases,   const float* __restrict__ thick_mult,
    const float* __restrict__ thick_bias,
    const float* __restrict__ dark_exp_p, const float* __restrict__ dark_nlw_p,
    const float* __restrict__ x_m_p,    const float* __restrict__ y_m_p,
    const float* __restrict__ x_b_p,    const float* __restrict__ y_b_p,
    float* __restrict__ out)
{
    __shared__ float4 s_A[NSEG];
    __shared__ float4 s_B[NSEG];

    const int b    = blockIdx.z;
    const int tid  = threadIdx.x;
    const int lane = tid & 63;

    const float dexp = dark_exp_p[0], dnlw = dark_nlw_p[0];

    float sy = 0.0f, sx = 0.0f, tk = 0.0f;
    const float tm = thick_mult[0], tb = thick_bias[0];
    if (lane < N_) {
        const float thv = theta[0];
        const float c   = __cosf(thv), s = __sinf(thv);
        const float xs  = x_start[0], ys = y_start[0];
        const float W00 = weights[0], W01 = weights[1];
        const float W10 = weights[2], W11 = weights[3];
        const float bb0 = biases[0],  bb1 = biases[1];
        const float xm  = x_m_p[0], ym = y_m_p[0];
        const float xb  = x_b_p[0], yb = y_b_p[0];
        float p0 = param[(b * N_ + lane) * 3 + 0];
        float p1 = param[(b * N_ + lane) * 3 + 1];
        float p2 = param[(b * N_ + lane) * 3 + 2];
        float x0 = p0, y0 = -p1;
        float x_rot =  x0 * c + y0 * s;
        float y_rot = -x0 * s + y0 * c;
        float yy = y_rot * ym + yb + ys;
        float xx = x_rot * xm + xb + xs;
        sy = yy * W00 + xx * W01 + bb0;
        sx = yy * W10 + xx * W11 + bb1;
        tk = (p2 * 2.0f + 0.5f) * (1.0f / 64.0f);
    }
    float sy1 = __shfl_down(sy, 1);
    float sx1 = __shfl_down(sx, 1);
    float tk1 = __shfl_down(tk, 1);

    bool keep = false;
    float4 A4 = make_float4(0,0,0,0), B4 = make_float4(0,0,0,0);
    if (lane < NSEG) {
        float wvy = sy1 - sy, wvx = sx1 - sx;
        float d2 = wvy * wvy + wvx * wvx;
        float inv_d2 = 1.0f / (d2 + 1e-5f);
        float c0 = tk * tm + tb;
        float c1 = (tk1 - tk) * tm;
        A4 = make_float4(sy, sx, wvy, wvx);
        B4 = make_float4(inv_d2, c0, c1, wvx * inv_d2 * (1.0f / W_));
        float thmax = fmaxf(fmaxf(c0, c0 + c1), 1e-8f);
        const float cy = ((float)(blockIdx.y * TSY) + 7.5f)  * (1.0f / H_);
        const float cx = ((float)(blockIdx.x * TSX) + 15.5f) * (1.0f / W_);
        float dyc = cy - sy, dxc = cx - sx;
        float dot = (dyc * wvy + dxc * wvx) * inv_d2;
        float fr  = __builtin_amdgcn_fmed3f(dot, 0.0f, 1.0f);
        float ey  = dyc - fr * wvy;
        float ex  = dxc - fr * wvx;
        float e2c = ey * ey + ex * ex;
        float reach = thmax + TILE_RAD;
        keep = e2c < reach * reach;
    }
    unsigned long long mask = __ballot(keep);
    const int cnt = (int)__popcll(mask);
    if (keep) {
        int pos = (int)__popcll(mask & ((1ull << lane) - 1ull));
        s_A[pos] = A4; s_B[pos] = B4;
    }
    asm volatile("s_waitcnt lgkmcnt(0)" ::: "memory");

    const int ii = tid >> 3;
    const int jj = tid & 7;
    const int r  = blockIdx.y * TSY + ii;
    const int c0 = blockIdx.x * TSX + (jj << 2);
    const float py  = (float)r  * (1.0f / H_);
    const float px0 = (float)c0 * (1.0f / W_);

    const bool hoist = (dexp > 0.0f) && (dnlw >= 0.0f) && (dnlw <= 1.0f);

    float o0, o1, o2, o3;
    if (hoist) {
        float q0 = INFINITY, q1 = INFINITY, q2 = INFINITY, q3 = INFINITY;
        if (cnt > 0) {
            float4 A = s_A[0], Bc = s_B[0];
            for (int n = 0; n < cnt; ++n) {
                int np = (n + 1 < cnt) ? n + 1 : n;
                float4 An = s_A[np], Bn = s_B[np];
                float dy  = py  - A.x;
                float dx0 = px0 - A.y;
                float dx1 = dx0 + 1.0f / W_;
                float dx2 = dx0 + 2.0f / W_;
                float dx3 = dx0 + 3.0f / W_;
                float dot0 = fmaf(dy, A.z, dx0 * A.w) * Bc.x;
                float dot1 = dot0 + Bc.w;
                float dot2 = dot1 + Bc.w;
                float dot3 = dot2 + Bc.w;
                #define PX(dotv, dxv, qm) { \
                    float fr = __builtin_amdgcn_fmed3f(dotv, 0.0f, 1.0f); \
                    float ey = fmaf(-fr, A.z, dy); \
                    float ex = fmaf(-fr, A.w, dxv); \
                    float e2 = fmaf(ey, ey, ex * ex); \
                    float th = fmaxf(fmaf(fr, Bc.z, Bc.y), 1e-8f); \
                    float it = __builtin_amdgcn_rcpf(th); \
                    qm = fminf(qm, (e2 * it) * it); }
                PX(dot0, dx0, q0)
                PX(dot1, dx1, q1)
                PX(dot2, dx2, q2)
                PX(dot3, dx3, q3)
                #undef PX
                A = An; Bc = Bn;
            }
        }
        const bool lin = (dexp == 1.0f);
        #define EPI(qm, rr) { \
            float md = fminf(fmaxf(1.0f - __builtin_amdgcn_sqrtf(qm), 0.0f), 1.0f); \
            float d  = lin ? (md + 1e-4f) : __expf(dexp * __logf(md + 1e-4f)); \
            float nl = __builtin_amdgcn_rcpf(1.0f + __expf(8.0f - d * 16.0f)); \
            rr = dnlw * nl + (1.0f - dnlw) * d; }
        EPI(q0, o0) EPI(q1, o1) EPI(q2, o2) EPI(q3, o3)
        #undef EPI
    } else {
        float b0 = -INFINITY, b1 = -INFINITY, b2 = -INFINITY, b3 = -INFINITY;
        if (cnt < NSEG) {
            float d0  = __expf(dexp * __logf(1e-4f));
            float nl0 = __builtin_amdgcn_rcpf(1.0f + __expf(8.0f - d0 * 16.0f));
            float t0  = dnlw * nl0 + (1.0f - dnlw) * d0;
            b0 = b1 = b2 = b3 = t0;
        }
        for (int n = 0; n < cnt; ++n) {
            float4 A = s_A[n], Bc = s_B[n];
            float dy  = py  - A.x;
            float dx0 = px0 - A.y;
            float dx1 = dx0 + 1.0f / W_;
            float dx2 = dx0 + 2.0f / W_;
            float dx3 = dx0 + 3.0f / W_;
            float dot0 = fmaf(dy, A.z, dx0 * A.w) * Bc.x;
            float dot1 = dot0 + Bc.w;
            float dot2 = dot1 + Bc.w;
            float dot3 = dot2 + Bc.w;
            #define PXF(dotv, dxv, bb) { \
                float fr = __builtin_amdgcn_fmed3f(dotv, 0.0f, 1.0f); \
                float ey = fmaf(-fr, A.z, dy); \
                float ex = fmaf(-fr, A.w, dxv); \
                float dist = __builtin_amdgcn_sqrtf(fmaf(ey, ey, ex * ex)); \
                float th = fmaxf(fmaf(fr, Bc.z, Bc.y), 1e-8f); \
                float dark = fminf(fmaxf(fmaf(-dist, __builtin_amdgcn_rcpf(th), 1.0f), 0.0f), 1.0f); \
                float d  = __expf(dexp * __logf(dark + 1e-4f)); \
                float nl = __builtin_amdgcn_rcpf(1.0f + __expf(8.0f - d * 16.0f)); \
                bb = fmaxf(bb, dnlw * nl + (1.0f - dnlw) * d); }
            PXF(dot0, dx0, b0)
            PXF(dot1, dx1, b1)
            PXF(dot2, dx2, b2)
            PXF(dot3, dx3, b3)
            #undef PXF
        }
        o0 = b0; o1 = b1; o2 = b2; o3 = b3;
    }

    if (r < H_ && c0 < W_) {
        *reinterpret_cast<float4*>(&out[(b * H_ + r) * W_ + c0]) =
            make_float4(o0, o1, o2, o3);
    }
}

extern "C" void kernel_launch(void* const* d_in, const int* in_sizes, int n_in,
                              void* d_out, int out_size, void* d_ws, size_t ws_size,
                              hipStream_t stream) {
    const float* param      = (const float*)d_in[0];
    const float* x_start    = (const float*)d_in[1];
    const float* y_start    = (const float*)d_in[2];
    const float* theta      = (const float*)d_in[3];
    const float* weights    = (const float*)d_in[4];
    const float* biases     = (const float*)d_in[5];
    const float* thick_mult = (const float*)d_in[6];
    const float* thick_bias = (const float*)d_in[7];
    const float* dark_exp   = (const float*)d_in[8];
    const float* dark_nlw   = (const float*)d_in[9];
    const float* x_m        = (const float*)d_in[10];
    const float* y_m        = (const float*)d_in[11];
    const float* x_b        = (const float*)d_in[12];
    const float* y_b        = (const float*)d_in[13];
    float* out = (float*)d_out;

    if (ws_size >= (size_t)WS_NEEDED) {
        unsigned* ws_mask = (unsigned*)d_ws;
        float4*   ws_segA = (float4*)((char*)d_ws + WS_SEGA_OFF);
        float4*   ws_segB = (float4*)((char*)d_ws + WS_SEGB_OFF);

        cull_kernel<<<dim3(NT2, B_), dim3(64), 0, stream>>>(
            param, x_start, y_start, theta, weights, biases,
            thick_mult, thick_bias, x_m, y_m, x_b, y_b,
            ws_mask, ws_segA, ws_segB);

        paint_kernel<<<dim3((NTILE + 3) / 4, B_), dim3(256), 0, stream>>>(
            dark_exp, dark_nlw, ws_mask, ws_segA, ws_segB, out);
    } else {
        stroke_mono<<<dim3(NTX, NTY, B_), dim3(128), 0, stream>>>(
            param, x_start, y_start, theta, weights, biases,
            thick_mult, thick_bias, dark_exp, dark_nlw,
            x_m, y_m, x_b, y_b, out);
    }
}

// Round 9
// 13.551 us; speedup vs baseline: 1.3433x; 1.3433x over previous
//
#include <hip/hip_runtime.h>
#include <math.h>

#define B_ 64
#define N_ 32
#define H_ 200
#define W_ 200
#define NSEG (N_ - 1)
#define NTX 7                 // block tile 32 wide (2 wave-tiles of 16)
#define NTY 13                // block tile 16 tall
// wave tile = 16x16 px; half-diagonal sqrt(7.5^2+7.5^2)/200 = 0.05303 + margin
#define TILE_RAD 0.054f

__global__ __launch_bounds__(128) void stroke_kernel(
    const float* __restrict__ param,      // (B, N, 3)
    const float* __restrict__ x_start,
    const float* __restrict__ y_start,
    const float* __restrict__ theta,
    const float* __restrict__ weights,    // (2,2)
    const float* __restrict__ biases,     // (2,)
    const float* __restrict__ thick_mult,
    const float* __restrict__ thick_bias,
    const float* __restrict__ dark_exp_p,
    const float* __restrict__ dark_nlw_p,
    const float* __restrict__ x_m_p,
    const float* __restrict__ y_m_p,
    const float* __restrict__ x_b_p,
    const float* __restrict__ y_b_p,
    float* __restrict__ out)              // (B, H, W)
{
    // Each wave owns a 16x16 tile and its own LDS slice: no cross-wave
    // sharing at all -> no barrier; in-wave lgkmcnt ordering suffices.
    __shared__ float4 s_A[2][NSEG];   // (vy, vx, wvy, wvx)
    __shared__ float4 s_B[2][NSEG];   // (inv_d2, c0, c1, ddot_x)

    const int b    = blockIdx.z;
    const int tid  = threadIdx.x;
    const int wid  = tid >> 6;            // 0,1: which 16-wide half
    const int lane = tid & 63;

    const int tile_c = blockIdx.x * 32 + wid * 16;
    const int tile_r = blockIdx.y * 16;
    if (tile_c >= W_) return;             // fully-OOB wave (bx=6, wid=1)

    const float dexp = dark_exp_p[0], dnlw = dark_nlw_p[0];

    // ---- per-wave setup (lanes 0..31 active in the math) ----
    float sy = 0.0f, sx = 0.0f, tk = 0.0f;
    const float tm = thick_mult[0], tb = thick_bias[0];
    if (lane < N_) {
        const float thv = theta[0];
        const float c   = __cosf(thv), s = __sinf(thv);   // native v_cos/v_sin
        const float xs  = x_start[0], ys = y_start[0];
        const float W00 = weights[0], W01 = weights[1];
        const float W10 = weights[2], W11 = weights[3];
        const float bb0 = biases[0],  bb1 = biases[1];
        const float xm  = x_m_p[0], ym = y_m_p[0];
        const float xb  = x_b_p[0], yb = y_b_p[0];
        float p0 = param[(b * N_ + lane) * 3 + 0];
        float p1 = param[(b * N_ + lane) * 3 + 1];
        float p2 = param[(b * N_ + lane) * 3 + 2];
        float x0 = p0, y0 = -p1;
        float x_rot =  x0 * c + y0 * s;
        float y_rot = -x0 * s + y0 * c;
        float yy = y_rot * ym + yb + ys;
        float xx = x_rot * xm + xb + xs;
        sy = yy * W00 + xx * W01 + bb0;
        sx = yy * W10 + xx * W11 + bb1;
        tk = (p2 * 2.0f + 0.5f) * (1.0f / 64.0f);
    }
    float sy1 = __shfl_down(sy, 1);
    float sx1 = __shfl_down(sx, 1);
    float tk1 = __shfl_down(tk, 1);

    bool keep = false;
    float4 A4 = make_float4(0,0,0,0), B4 = make_float4(0,0,0,0);
    if (lane < NSEG) {
        float wvy = sy1 - sy, wvx = sx1 - sx;
        float d2 = wvy * wvy + wvx * wvx;
        float inv_d2 = 1.0f / (d2 + 1e-5f);
        float c0 = tk * tm + tb;            // th(frac) = c0 + frac*c1
        float c1 = (tk1 - tk) * tm;
        A4 = make_float4(sy, sx, wvy, wvx);
        B4 = make_float4(inv_d2, c0, c1, wvx * inv_d2 * (1.0f / W_));
        float thmax = fmaxf(fmaxf(c0, c0 + c1), 1e-8f);
        // circle cull around THIS WAVE's 16x16 tile center
        const float cy = ((float)tile_r + 7.5f) * (1.0f / H_);
        const float cx = ((float)tile_c + 7.5f) * (1.0f / W_);
        float dyc = cy - sy, dxc = cx - sx;
        float dot = (dyc * wvy + dxc * wvx) * inv_d2;
        float fr  = __builtin_amdgcn_fmed3f(dot, 0.0f, 1.0f);
        float ey  = dyc - fr * wvy;
        float ex  = dxc - fr * wvx;
        float e2c = ey * ey + ex * ex;
        float reach = thmax + TILE_RAD;     // beyond -> dark==0 in whole tile
        keep = e2c < reach * reach;
    }
    unsigned long long mask = __ballot(keep);
    const int cnt = (int)__popcll(mask);
    if (keep) {
        int pos = (int)__popcll(mask & ((1ull << lane) - 1ull));
        s_A[wid][pos] = A4; s_B[wid][pos] = B4;
    }
    // order this wave's own LDS writes before its reads
    asm volatile("s_waitcnt lgkmcnt(0)" ::: "memory");

    // ---- 1 row x 4 adjacent cols per lane; wave = 16 rows x 16 cols ----
    const int r  = tile_r + (lane >> 2);
    const int c0 = tile_c + ((lane & 3) << 2);
    const float py  = (float)r  * (1.0f / H_);
    const float px0 = (float)c0 * (1.0f / W_);

    const bool hoist = (dexp > 0.0f) && (dnlw >= 0.0f) && (dnlw <= 1.0f);

    float o0, o1, o2, o3;
    if (hoist) {
        // maximize dark = 1 - sqrt(e2)/th  <=>  minimize q = e2*rcp(th)^2;
        // sqrt once per pixel; final clamp01 subsumes per-seg clamp + culled 0s.
        float q0 = INFINITY, q1 = INFINITY, q2 = INFINITY, q3 = INFINITY;
        if (cnt > 0) {
            float4 A = s_A[wid][0], Bc = s_B[wid][0];
            for (int n = 0; n < cnt; ++n) {
                int np = (n + 1 < cnt) ? n + 1 : n;   // prefetch next
                float4 An = s_A[wid][np], Bn = s_B[wid][np];
                float dy  = py  - A.x;
                float dx0 = px0 - A.y;
                float dx1 = dx0 + 1.0f / W_;
                float dx2 = dx0 + 2.0f / W_;
                float dx3 = dx0 + 3.0f / W_;
                float dot0 = fmaf(dy, A.z, dx0 * A.w) * Bc.x;
                float dot1 = dot0 + Bc.w;
                float dot2 = dot1 + Bc.w;
                float dot3 = dot2 + Bc.w;
                #define PX(dotv, dxv, qm) { \
                    float fr = __builtin_amdgcn_fmed3f(dotv, 0.0f, 1.0f); \
                    float ey = fmaf(-fr, A.z, dy); \
                    float ex = fmaf(-fr, A.w, dxv); \
                    float e2 = fmaf(ey, ey, ex * ex); \
                    float th = fmaxf(fmaf(fr, Bc.z, Bc.y), 1e-8f); \
                    float it = __builtin_amdgcn_rcpf(th); \
                    qm = fminf(qm, (e2 * it) * it); }
                PX(dot0, dx0, q0)
                PX(dot1, dx1, q1)
                PX(dot2, dx2, q2)
                PX(dot3, dx3, q3)
                #undef PX
                A = An; Bc = Bn;
            }
        }
        const bool lin = (dexp == 1.0f);     // uniform: skip pow entirely
        #define EPI(qm, rr) { \
            float md = fminf(fmaxf(1.0f - __builtin_amdgcn_sqrtf(qm), 0.0f), 1.0f); \
            float d  = lin ? (md + 1e-4f) : __expf(dexp * __logf(md + 1e-4f)); \
            float nl = __builtin_amdgcn_rcpf(1.0f + __expf(8.0f - d * 16.0f)); \
            rr = dnlw * nl + (1.0f - dnlw) * d; }
        EPI(q0, o0) EPI(q1, o1) EPI(q2, o2) EPI(q3, o3)
        #undef EPI
    } else {
        // generic fallback: per-segment transform; culled segs contribute T(0)
        float b0 = -INFINITY, b1 = -INFINITY, b2 = -INFINITY, b3 = -INFINITY;
        if (cnt < NSEG) {
            float d0  = __expf(dexp * __logf(1e-4f));
            float nl0 = __builtin_amdgcn_rcpf(1.0f + __expf(8.0f - d0 * 16.0f));
            float t0  = dnlw * nl0 + (1.0f - dnlw) * d0;
            b0 = b1 = b2 = b3 = t0;
        }
        for (int n = 0; n < cnt; ++n) {
            float4 A = s_A[wid][n], Bc = s_B[wid][n];
            float dy  = py  - A.x;
            float dx0 = px0 - A.y;
            float dx1 = dx0 + 1.0f / W_;
            float dx2 = dx0 + 2.0f / W_;
            float dx3 = dx0 + 3.0f / W_;
            float dot0 = fmaf(dy, A.z, dx0 * A.w) * Bc.x;
            float dot1 = dot0 + Bc.w;
            float dot2 = dot1 + Bc.w;
            float dot3 = dot2 + Bc.w;
            #define PXF(dotv, dxv, bb) { \
                float fr = __builtin_amdgcn_fmed3f(dotv, 0.0f, 1.0f); \
                float ey = fmaf(-fr, A.z, dy); \
                float ex = fmaf(-fr, A.w, dxv); \
                float dist = __builtin_amdgcn_sqrtf(fmaf(ey, ey, ex * ex)); \
                float th = fmaxf(fmaf(fr, Bc.z, Bc.y), 1e-8f); \
                float dark = fminf(fmaxf(fmaf(-dist, __builtin_amdgcn_rcpf(th), 1.0f), 0.0f), 1.0f); \
                float d  = __expf(dexp * __logf(dark + 1e-4f)); \
                float nl = __builtin_amdgcn_rcpf(1.0f + __expf(8.0f - d * 16.0f)); \
                bb = fmaxf(bb, dnlw * nl + (1.0f - dnlw) * d); }
            PXF(dot0, dx0, b0)
            PXF(dot1, dx1, b1)
            PXF(dot2, dx2, b2)
            PXF(dot3, dx3, b3)
            #undef PXF
        }
        o0 = b0; o1 = b1; o2 = b2; o3 = b3;
    }

    if (r < H_ && c0 < W_) {   // c0 % 4 == 0, W % 4 == 0 -> quad never straddles
        *reinterpret_cast<float4*>(&out[(b * H_ + r) * W_ + c0]) =
            make_float4(o0, o1, o2, o3);
    }
}

extern "C" void kernel_launch(void* const* d_in, const int* in_sizes, int n_in,
                              void* d_out, int out_size, void* d_ws, size_t ws_size,
                              hipStream_t stream) {
    const float* param      = (const float*)d_in[0];
    const float* x_start    = (const float*)d_in[1];
    const float* y_start    = (const float*)d_in[2];
    const float* theta      = (const float*)d_in[3];
    const float* weights    = (const float*)d_in[4];
    const float* biases     = (const float*)d_in[5];
    const float* thick_mult = (const float*)d_in[6];
    const float* thick_bias = (const float*)d_in[7];
    const float* dark_exp   = (const float*)d_in[8];
    const float* dark_nlw   = (const float*)d_in[9];
    const float* x_m        = (const float*)d_in[10];
    const float* y_m        = (const float*)d_in[11];
    const float* x_b        = (const float*)d_in[12];
    const float* y_b        = (const float*)d_in[13];
    float* out = (float*)d_out;

    dim3 block(128);
    dim3 grid(NTX, NTY, B_);
    stroke_kernel<<<grid, block, 0, stream>>>(
        param, x_start, y_start, theta, weights, biases,
        thick_mult, thick_bias, dark_exp, dark_nlw,
        x_m, y_m, x_b, y_b, out);
}

// Round 10
// 13.551 us; speedup vs baseline: 1.3434x; 1.0000x over previous
//
#include <hip/hip_runtime.h>
#include <math.h>

#define B_ 64
#define N_ 32
#define H_ 200
#define W_ 200
#define NSEG (N_ - 1)
#define NTX 7                 // block tile 32 wide (2 wave-tiles of 16)
#define NTY 13                // block tile 16 tall
// wave tile = 16x16 px; half-diagonal sqrt(7.5^2+7.5^2)/200 = 0.05303 + margin
#define TILE_RAD 0.054f

// Inner loop over kept segments for 4 adjacent pixels of one row.
// Minimizes q = e2/th^2 via cross-multiplied pair (e2m, t2m): no per-pixel
// rcp; the single rcp happens in the caller's epilogue.
template<bool CLAMP>
__device__ __forceinline__ void seg_loop(
    const float4* __restrict__ sA, const float4* __restrict__ sB, int cnt,
    float py, float px0, float& q0, float& q1, float& q2, float& q3)
{
    float e0 = INFINITY, e1 = INFINITY, e2_ = INFINITY, e3 = INFINITY;
    float t0 = 1.0f,     t1 = 1.0f,     t2_ = 1.0f,     t3 = 1.0f;
    #pragma unroll 2
    for (int n = 0; n < cnt; ++n) {
        float4 A = sA[n], Bc = sB[n];
        float dy  = py  - A.x;
        float dx0 = px0 - A.y;
        float dx1 = dx0 + 1.0f / W_;
        float dx2 = dx0 + 2.0f / W_;
        float dx3 = dx0 + 3.0f / W_;
        float dot0 = fmaf(dy, A.z, dx0 * A.w) * Bc.x;
        float dot1 = dot0 + Bc.w;
        float dot2 = dot1 + Bc.w;
        float dot3 = dot2 + Bc.w;
        #define PXN(dotv, dxv, EM, TM) { \
            float fr = __builtin_amdgcn_fmed3f(dotv, 0.0f, 1.0f); \
            float ey = fmaf(-fr, A.z, dy); \
            float ex = fmaf(-fr, A.w, dxv); \
            float e2 = fmaf(ey, ey, ex * ex); \
            float th = fmaf(fr, Bc.z, Bc.y); \
            if (CLAMP) th = fmaxf(th, 1e-8f); \
            float tt = th * th; \
            bool lt = e2 * TM < EM * tt; \
            EM = lt ? e2 : EM; \
            TM = lt ? tt : TM; }
        PXN(dot0, dx0, e0, t0)
        PXN(dot1, dx1, e1, t1)
        PXN(dot2, dx2, e2_, t2_)
        PXN(dot3, dx3, e3, t3)
        #undef PXN
    }
    q0 = e0  * __builtin_amdgcn_rcpf(t0);
    q1 = e1  * __builtin_amdgcn_rcpf(t1);
    q2 = e2_ * __builtin_amdgcn_rcpf(t2_);
    q3 = e3  * __builtin_amdgcn_rcpf(t3);
}

__global__ __launch_bounds__(128) void stroke_kernel(
    const float* __restrict__ param,      // (B, N, 3)
    const float* __restrict__ x_start,
    const float* __restrict__ y_start,
    const float* __restrict__ theta,
    const float* __restrict__ weights,    // (2,2)
    const float* __restrict__ biases,     // (2,)
    const float* __restrict__ thick_mult,
    const float* __restrict__ thick_bias,
    const float* __restrict__ dark_exp_p,
    const float* __restrict__ dark_nlw_p,
    const float* __restrict__ x_m_p,
    const float* __restrict__ y_m_p,
    const float* __restrict__ x_b_p,
    const float* __restrict__ y_b_p,
    float* __restrict__ out)              // (B, H, W)
{
    // Each wave owns a 16x16 tile and its own LDS slice: no cross-wave
    // sharing -> no barrier; in-wave lgkmcnt ordering suffices.
    __shared__ float4 s_A[2][NSEG];   // (vy, vx, wvy, wvx)
    __shared__ float4 s_B[2][NSEG];   // (inv_d2, c0, c1, ddot_x)

    const int b    = blockIdx.z;
    const int tid  = threadIdx.x;
    const int wid  = tid >> 6;            // 0,1: which 16-wide half
    const int lane = tid & 63;

    const int tile_c = blockIdx.x * 32 + wid * 16;
    const int tile_r = blockIdx.y * 16;
    if (tile_c >= W_) return;             // fully-OOB wave (bx=6, wid=1)

    const float dexp = dark_exp_p[0], dnlw = dark_nlw_p[0];

    // ---- per-wave setup (lanes 0..31 active in the math) ----
    float sy = 0.0f, sx = 0.0f, tk = 0.0f;
    const float tm = thick_mult[0], tb = thick_bias[0];
    if (lane < N_) {
        const float thv = theta[0];
        const float c   = __cosf(thv), s = __sinf(thv);   // native v_cos/v_sin
        const float xs  = x_start[0], ys = y_start[0];
        const float W00 = weights[0], W01 = weights[1];
        const float W10 = weights[2], W11 = weights[3];
        const float bb0 = biases[0],  bb1 = biases[1];
        const float xm  = x_m_p[0], ym = y_m_p[0];
        const float xb  = x_b_p[0], yb = y_b_p[0];
        float p0 = param[(b * N_ + lane) * 3 + 0];
        float p1 = param[(b * N_ + lane) * 3 + 1];
        float p2 = param[(b * N_ + lane) * 3 + 2];
        float x0 = p0, y0 = -p1;
        float x_rot =  x0 * c + y0 * s;
        float y_rot = -x0 * s + y0 * c;
        float yy = y_rot * ym + yb + ys;
        float xx = x_rot * xm + xb + xs;
        sy = yy * W00 + xx * W01 + bb0;
        sx = yy * W10 + xx * W11 + bb1;
        tk = (p2 * 2.0f + 0.5f) * (1.0f / 64.0f);
    }
    float sy1 = __shfl_down(sy, 1);
    float sx1 = __shfl_down(sx, 1);
    float tk1 = __shfl_down(tk, 1);

    bool keep = false;
    bool tiny = false;   // th clamp could activate for this segment
    float4 A4 = make_float4(0,0,0,0), B4 = make_float4(0,0,0,0);
    if (lane < NSEG) {
        float wvy = sy1 - sy, wvx = sx1 - sx;
        float d2 = wvy * wvy + wvx * wvx;
        float inv_d2 = 1.0f / (d2 + 1e-5f);
        float c0 = tk * tm + tb;            // th(frac) = c0 + frac*c1
        float c1 = (tk1 - tk) * tm;
        A4 = make_float4(sy, sx, wvy, wvx);
        B4 = make_float4(inv_d2, c0, c1, wvx * inv_d2 * (1.0f / W_));
        float thmax = fmaxf(fmaxf(c0, c0 + c1), 1e-8f);
        tiny = fminf(c0, c0 + c1) <= 1e-8f;
        // circle cull around THIS WAVE's 16x16 tile center
        const float cy = ((float)tile_r + 7.5f) * (1.0f / H_);
        const float cx = ((float)tile_c + 7.5f) * (1.0f / W_);
        float dyc = cy - sy, dxc = cx - sx;
        float dot = (dyc * wvy + dxc * wvx) * inv_d2;
        float fr  = __builtin_amdgcn_fmed3f(dot, 0.0f, 1.0f);
        float ey  = dyc - fr * wvy;
        float ex  = dxc - fr * wvx;
        float e2c = ey * ey + ex * ex;
        float reach = thmax + TILE_RAD;     // beyond -> dark==0 in whole tile
        keep = e2c < reach * reach;
    }
    unsigned long long mask = __ballot(keep);
    const int cnt = (int)__popcll(mask);
    const bool needClamp = __any(keep && tiny);
    if (keep) {
        int pos = (int)__popcll(mask & ((1ull << lane) - 1ull));
        s_A[wid][pos] = A4; s_B[wid][pos] = B4;
    }
    // order this wave's own LDS writes before its reads
    asm volatile("s_waitcnt lgkmcnt(0)" ::: "memory");

    // ---- 1 row x 4 adjacent cols per lane; wave = 16 rows x 16 cols ----
    const int r  = tile_r + (lane >> 2);
    const int c0 = tile_c + ((lane & 3) << 2);
    const float py  = (float)r  * (1.0f / H_);
    const float px0 = (float)c0 * (1.0f / W_);

    const bool hoist = (dexp > 0.0f) && (dnlw >= 0.0f) && (dnlw <= 1.0f);

    float o0, o1, o2, o3;
    if (hoist) {
        // maximize dark = 1 - sqrt(e2)/th  <=>  minimize q = e2/th^2;
        // sqrt/rcp once per pixel in epilogue; final clamp01 subsumes the
        // per-seg clamp (monotone) and culled segments' zeros.
        float q0, q1, q2, q3;
        if (needClamp)
            seg_loop<true >(s_A[wid], s_B[wid], cnt, py, px0, q0, q1, q2, q3);
        else
            seg_loop<false>(s_A[wid], s_B[wid], cnt, py, px0, q0, q1, q2, q3);
        const bool lin = (dexp == 1.0f);     // uniform: skip pow entirely
        #define EPI(qm, rr) { \
            float md = fminf(fmaxf(1.0f - __builtin_amdgcn_sqrtf(qm), 0.0f), 1.0f); \
            float d  = lin ? (md + 1e-4f) : __expf(dexp * __logf(md + 1e-4f)); \
            float nl = __builtin_amdgcn_rcpf(1.0f + __expf(8.0f - d * 16.0f)); \
            rr = dnlw * nl + (1.0f - dnlw) * d; }
        EPI(q0, o0) EPI(q1, o1) EPI(q2, o2) EPI(q3, o3)
        #undef EPI
    } else {
        // generic fallback: per-segment transform; culled segs contribute T(0)
        float b0 = -INFINITY, b1 = -INFINITY, b2 = -INFINITY, b3 = -INFINITY;
        if (cnt < NSEG) {
            float d0  = __expf(dexp * __logf(1e-4f));
            float nl0 = __builtin_amdgcn_rcpf(1.0f + __expf(8.0f - d0 * 16.0f));
            float t0  = dnlw * nl0 + (1.0f - dnlw) * d0;
            b0 = b1 = b2 = b3 = t0;
        }
        for (int n = 0; n < cnt; ++n) {
            float4 A = s_A[wid][n], Bc = s_B[wid][n];
            float dy  = py  - A.x;
            float dx0 = px0 - A.y;
            float dx1 = dx0 + 1.0f / W_;
            float dx2 = dx0 + 2.0f / W_;
            float dx3 = dx0 + 3.0f / W_;
            float dot0 = fmaf(dy, A.z, dx0 * A.w) * Bc.x;
            float dot1 = dot0 + Bc.w;
            float dot2 = dot1 + Bc.w;
            float dot3 = dot2 + Bc.w;
            #define PXF(dotv, dxv, bb) { \
                float fr = __builtin_amdgcn_fmed3f(dotv, 0.0f, 1.0f); \
                float ey = fmaf(-fr, A.z, dy); \
                float ex = fmaf(-fr, A.w, dxv); \
                float dist = __builtin_amdgcn_sqrtf(fmaf(ey, ey, ex * ex)); \
                float th = fmaxf(fmaf(fr, Bc.z, Bc.y), 1e-8f); \
                float dark = fminf(fmaxf(fmaf(-dist, __builtin_amdgcn_rcpf(th), 1.0f), 0.0f), 1.0f); \
                float d  = __expf(dexp * __logf(dark + 1e-4f)); \
                float nl = __builtin_amdgcn_rcpf(1.0f + __expf(8.0f - d * 16.0f)); \
                bb = fmaxf(bb, dnlw * nl + (1.0f - dnlw) * d); }
            PXF(dot0, dx0, b0)
            PXF(dot1, dx1, b1)
            PXF(dot2, dx2, b2)
            PXF(dot3, dx3, b3)
            #undef PXF
        }
        o0 = b0; o1 = b1; o2 = b2; o3 = b3;
    }

    if (r < H_ && c0 < W_) {   // c0 % 4 == 0, W % 4 == 0 -> quad never straddles
        *reinterpret_cast<float4*>(&out[(b * H_ + r) * W_ + c0]) =
            make_float4(o0, o1, o2, o3);
    }
}

extern "C" void kernel_launch(void* const* d_in, const int* in_sizes, int n_in,
                              void* d_out, int out_size, void* d_ws, size_t ws_size,
                              hipStream_t stream) {
    const float* param      = (const float*)d_in[0];
    const float* x_start    = (const float*)d_in[1];
    const float* y_start    = (const float*)d_in[2];
    const float* theta      = (const float*)d_in[3];
    const float* weights    = (const float*)d_in[4];
    const float* biases     = (const float*)d_in[5];
    const float* thick_mult = (const float*)d_in[6];
    const float* thick_bias = (const float*)d_in[7];
    const float* dark_exp   = (const float*)d_in[8];
    const float* dark_nlw   = (const float*)d_in[9];
    const float* x_m        = (const float*)d_in[10];
    const float* y_m        = (const float*)d_in[11];
    const float* x_b        = (const float*)d_in[12];
    const float* y_b        = (const float*)d_in[13];
    float* out = (float*)d_out;

    dim3 block(128);
    dim3 grid(NTX, NTY, B_);
    stroke_kernel<<<grid, block, 0, stream>>>(
        param, x_start, y_start, theta, weights, biases,
        thick_mult, thick_bias, dark_exp, dark_nlw,
        x_m, y_m, x_b, y_b, out);
}